// Round 7
// baseline (389.032 us; speedup 1.0000x reference)
//
#include <hip/hip_runtime.h>

// ---------------- Broadcast-5 fused constants ----------------
#define PARTS 5
#define NPP 40960                  // nodes per partition; 5*40960 = 204800 >= 200000
#define PADDED_N (PARTS * NPP)     // 204800
#define NCHUNKS 51                 // 5*51 = 255 blocks -> 1 block/CU
#define TPB_SCAN 1024

typedef int   vint4   __attribute__((ext_vector_type(4)));
typedef float vfloat4 __attribute__((ext_vector_type(4)));

// ---------------- Fused phase: gather + 5-partition broadcast scan ----------------
// block (c,p): stream chunk c's (dst, src, widx) with NT loads; for edges whose
// dst lies in partition p (exec-masked, so each edge is gathered exactly once
// chip-wide), gather W/x, multiply, LDS-accumulate. Flush to partials[c].
// Gather latency hides under the stream/LDS work; W (4MB) + x (800KB) stay
// L2-resident because all streaming traffic is non-temporal.
__global__ __launch_bounds__(TPB_SCAN) void fscan_kernel(
    const float* __restrict__ x, const float* __restrict__ W,
    const int* __restrict__ src, const int* __restrict__ widx,
    const int* __restrict__ dst,
    float* __restrict__ partials, int E, int chunk)
{
    extern __shared__ float acc[];   // NPP floats = 160 KB
    int p = blockIdx.x % PARTS;
    int c = blockIdx.x / PARTS;

    float4* a4 = reinterpret_cast<float4*>(acc);
    for (int i = threadIdx.x; i < NPP / 4; i += TPB_SCAN)
        a4[i] = make_float4(0.f, 0.f, 0.f, 0.f);
    __syncthreads();

    int lo = c * chunk;              // chunk is a multiple of 4
    int hi = min(E, lo + chunk);     // E is a multiple of 4
    int base = p * NPP;

    const vint4* d4 = reinterpret_cast<const vint4*>(dst);
    const vint4* s4 = reinterpret_cast<const vint4*>(src);
    const vint4* w4 = reinterpret_cast<const vint4*>(widx);

    #pragma unroll 2
    for (int g = lo / 4 + threadIdx.x; g < hi / 4; g += TPB_SCAN) {
        vint4 d = __builtin_nontemporal_load(d4 + g);
        vint4 s = __builtin_nontemporal_load(s4 + g);
        vint4 w = __builtin_nontemporal_load(w4 + g);

        unsigned r0 = (unsigned)(d.x - base);
        unsigned r1 = (unsigned)(d.y - base);
        unsigned r2 = (unsigned)(d.z - base);
        unsigned r3 = (unsigned)(d.w - base);

        // issue all owned gathers first (exec-masked), then the LDS atomics
        float m0 = 0.f, m1 = 0.f, m2 = 0.f, m3 = 0.f;
        if (r0 < NPP) m0 = W[w.x] * x[s.x];
        if (r1 < NPP) m1 = W[w.y] * x[s.y];
        if (r2 < NPP) m2 = W[w.z] * x[s.z];
        if (r3 < NPP) m3 = W[w.w] * x[s.w];
        if (r0 < NPP) atomicAdd(&acc[r0], m0);
        if (r1 < NPP) atomicAdd(&acc[r1], m1);
        if (r2 < NPP) atomicAdd(&acc[r2], m2);
        if (r3 < NPP) atomicAdd(&acc[r3], m3);
    }
    __syncthreads();

    vfloat4* out4 = reinterpret_cast<vfloat4*>(partials + (size_t)c * PADDED_N + base);
    const vfloat4* av4 = reinterpret_cast<const vfloat4*>(acc);
    for (int i = threadIdx.x; i < NPP / 4; i += TPB_SCAN)
        __builtin_nontemporal_store(av4[i], out4 + i);
}

// ---------------- Reduce: 51 slices + bias ----------------
__global__ __launch_bounds__(256) void reduce5_kernel(
    const float* __restrict__ partials, const float* __restrict__ bias,
    const int* __restrict__ label, float* __restrict__ y, int n)
{
    int i = blockIdx.x * 256 + threadIdx.x;
    if (i >= n) return;
    float s0 = bias[label[i]];
    float s1 = 0.f, s2 = 0.f, s3 = 0.f;
    const float* p = partials + i;
    #pragma unroll 1
    for (int c = 0; c + 3 < NCHUNKS; c += 4) {
        s0 += __builtin_nontemporal_load(p + (size_t)(c + 0) * PADDED_N);
        s1 += __builtin_nontemporal_load(p + (size_t)(c + 1) * PADDED_N);
        s2 += __builtin_nontemporal_load(p + (size_t)(c + 2) * PADDED_N);
        s3 += __builtin_nontemporal_load(p + (size_t)(c + 3) * PADDED_N);
    }
    // NCHUNKS = 51 = 48 + 3
    s0 += __builtin_nontemporal_load(p + (size_t)48 * PADDED_N);
    s1 += __builtin_nontemporal_load(p + (size_t)49 * PADDED_N);
    s2 += __builtin_nontemporal_load(p + (size_t)50 * PADDED_N);
    y[i] = (s0 + s1) + (s2 + s3);
}

// ---------------- Fallback (direct atomics) if ws too small ----------------
__global__ __launch_bounds__(256) void bias_init_kernel(
    const float* __restrict__ Param_b, const int* __restrict__ node_label,
    float* __restrict__ y, int n_nodes)
{
    int i = blockIdx.x * blockDim.x + threadIdx.x;
    if (i < n_nodes) y[i] = Param_b[node_label[i]];
}

__global__ __launch_bounds__(256) void edge_scatter_kernel(
    const float* __restrict__ x, const float* __restrict__ Param_W,
    const int* __restrict__ src, const int* __restrict__ dst,
    const int* __restrict__ widx, float* __restrict__ y, int n_edges)
{
    int i = (blockIdx.x * blockDim.x + threadIdx.x) * 4;
    if (i + 3 < n_edges) {
        int4 s = *reinterpret_cast<const int4*>(src + i);
        int4 d = *reinterpret_cast<const int4*>(dst + i);
        int4 w = *reinterpret_cast<const int4*>(widx + i);
        unsafeAtomicAdd(&y[d.x], Param_W[w.x] * x[s.x]);
        unsafeAtomicAdd(&y[d.y], Param_W[w.y] * x[s.y]);
        unsafeAtomicAdd(&y[d.z], Param_W[w.z] * x[s.z]);
        unsafeAtomicAdd(&y[d.w], Param_W[w.w] * x[s.w]);
    } else {
        for (; i < n_edges; ++i)
            unsafeAtomicAdd(&y[dst[i]], Param_W[widx[i]] * x[src[i]]);
    }
}

extern "C" void kernel_launch(void* const* d_in, const int* in_sizes, int n_in,
                              void* d_out, int out_size, void* d_ws, size_t ws_size,
                              hipStream_t stream)
{
    const float* x          = (const float*)d_in[0];
    const float* Param_W    = (const float*)d_in[1];
    const float* Param_b    = (const float*)d_in[2];
    const int*   src        = (const int*)d_in[3];
    const int*   dst        = (const int*)d_in[4];
    const int*   weight_idx = (const int*)d_in[5];
    const int*   node_label = (const int*)d_in[6];
    float* y = (float*)d_out;

    int n_nodes = in_sizes[0];
    int E       = in_sizes[3];

    size_t partials_elems = (size_t)NCHUNKS * PADDED_N;        // 41.8 MB
    size_t need_bytes     = partials_elems * sizeof(float);

    if (ws_size >= need_bytes) {
        float* partials = (float*)d_ws;

        // Fused gather + scan: 160 KB dynamic LDS per block, 1 block/CU
        int chunk = (((E + NCHUNKS - 1) / NCHUNKS) + 3) & ~3;  // mult of 4
        fscan_kernel<<<PARTS * NCHUNKS, TPB_SCAN, NPP * sizeof(float), stream>>>(
            x, Param_W, src, weight_idx, dst, partials, E, chunk);

        reduce5_kernel<<<(n_nodes + 255) / 256, 256, 0, stream>>>(
            partials, Param_b, node_label, y, n_nodes);
    } else {
        bias_init_kernel<<<(n_nodes + 255) / 256, 256, 0, stream>>>(
            Param_b, node_label, y, n_nodes);
        int t = (E + 3) / 4;
        edge_scatter_kernel<<<(t + 255) / 256, 256, 0, stream>>>(
            x, Param_W, src, dst, weight_idx, y, E);
    }
}

// Round 8
// 374.686 us; speedup vs baseline: 1.0383x; 1.0383x over previous
//
#include <hip/hip_runtime.h>

// ---------------- Broadcast-5 fused constants ----------------
#define PARTS 5
#define NPP 40960                  // nodes per partition; 5*40960 = 204800 >= 200000
#define PADDED_N (PARTS * NPP)     // 204800
#define NCHUNKS 51                 // 5*51 = 255 blocks -> 1 block/CU
#define TPB_SCAN 1024

typedef int   vint4   __attribute__((ext_vector_type(4)));
typedef float vfloat4 __attribute__((ext_vector_type(4)));

// ---------------- Fused phase: gather + 5-partition broadcast scan ----------------
// block (c,p): stream chunk c's (dst, src, widx) with PLAIN loads (L3 retains
// the chunk for the 5 co-scheduled partition readers — NT here was round-7's
// mistake: it killed LLC reuse and pushed 603 MB to HBM). For edges whose dst
// lies in partition p (exec-masked; each edge gathered exactly once chip-wide),
// gather W/x, multiply, LDS-accumulate. Flush to partials[c] with NT stores.
__global__ __launch_bounds__(TPB_SCAN) void fscan_kernel(
    const float* __restrict__ x, const float* __restrict__ W,
    const int* __restrict__ src, const int* __restrict__ widx,
    const int* __restrict__ dst,
    float* __restrict__ partials, int E, int chunk)
{
    extern __shared__ float acc[];   // NPP floats = 160 KB
    int p = blockIdx.x % PARTS;
    int c = blockIdx.x / PARTS;

    float4* a4 = reinterpret_cast<float4*>(acc);
    for (int i = threadIdx.x; i < NPP / 4; i += TPB_SCAN)
        a4[i] = make_float4(0.f, 0.f, 0.f, 0.f);
    __syncthreads();

    int lo = c * chunk;              // chunk is a multiple of 4
    int hi = min(E, lo + chunk);     // E is a multiple of 4
    int base = p * NPP;

    const vint4* d4 = reinterpret_cast<const vint4*>(dst);
    const vint4* s4 = reinterpret_cast<const vint4*>(src);
    const vint4* w4 = reinterpret_cast<const vint4*>(widx);

    #pragma unroll 4
    for (int g = lo / 4 + threadIdx.x; g < hi / 4; g += TPB_SCAN) {
        vint4 d = d4[g];
        vint4 s = s4[g];
        vint4 w = w4[g];

        unsigned r0 = (unsigned)(d.x - base);
        unsigned r1 = (unsigned)(d.y - base);
        unsigned r2 = (unsigned)(d.z - base);
        unsigned r3 = (unsigned)(d.w - base);

        // issue all owned gathers first (exec-masked), then the LDS atomics
        float m0 = 0.f, m1 = 0.f, m2 = 0.f, m3 = 0.f;
        if (r0 < NPP) m0 = W[w.x] * x[s.x];
        if (r1 < NPP) m1 = W[w.y] * x[s.y];
        if (r2 < NPP) m2 = W[w.z] * x[s.z];
        if (r3 < NPP) m3 = W[w.w] * x[s.w];
        if (r0 < NPP) atomicAdd(&acc[r0], m0);
        if (r1 < NPP) atomicAdd(&acc[r1], m1);
        if (r2 < NPP) atomicAdd(&acc[r2], m2);
        if (r3 < NPP) atomicAdd(&acc[r3], m3);
    }
    __syncthreads();

    vfloat4* out4 = reinterpret_cast<vfloat4*>(partials + (size_t)c * PADDED_N + base);
    const vfloat4* av4 = reinterpret_cast<const vfloat4*>(acc);
    for (int i = threadIdx.x; i < NPP / 4; i += TPB_SCAN)
        __builtin_nontemporal_store(av4[i], out4 + i);
}

// ---------------- Reduce: 51 slices + bias ----------------
__global__ __launch_bounds__(256) void reduce5_kernel(
    const float* __restrict__ partials, const float* __restrict__ bias,
    const int* __restrict__ label, float* __restrict__ y, int n)
{
    int i = blockIdx.x * 256 + threadIdx.x;
    if (i >= n) return;
    float s0 = bias[label[i]];
    float s1 = 0.f, s2 = 0.f, s3 = 0.f;
    const float* p = partials + i;
    #pragma unroll 1
    for (int c = 0; c + 3 < NCHUNKS; c += 4) {
        s0 += __builtin_nontemporal_load(p + (size_t)(c + 0) * PADDED_N);
        s1 += __builtin_nontemporal_load(p + (size_t)(c + 1) * PADDED_N);
        s2 += __builtin_nontemporal_load(p + (size_t)(c + 2) * PADDED_N);
        s3 += __builtin_nontemporal_load(p + (size_t)(c + 3) * PADDED_N);
    }
    // NCHUNKS = 51 = 48 + 3
    s0 += __builtin_nontemporal_load(p + (size_t)48 * PADDED_N);
    s1 += __builtin_nontemporal_load(p + (size_t)49 * PADDED_N);
    s2 += __builtin_nontemporal_load(p + (size_t)50 * PADDED_N);
    y[i] = (s0 + s1) + (s2 + s3);
}

// ---------------- Fallback (direct atomics) if ws too small ----------------
__global__ __launch_bounds__(256) void bias_init_kernel(
    const float* __restrict__ Param_b, const int* __restrict__ node_label,
    float* __restrict__ y, int n_nodes)
{
    int i = blockIdx.x * blockDim.x + threadIdx.x;
    if (i < n_nodes) y[i] = Param_b[node_label[i]];
}

__global__ __launch_bounds__(256) void edge_scatter_kernel(
    const float* __restrict__ x, const float* __restrict__ Param_W,
    const int* __restrict__ src, const int* __restrict__ dst,
    const int* __restrict__ widx, float* __restrict__ y, int n_edges)
{
    int i = (blockIdx.x * blockDim.x + threadIdx.x) * 4;
    if (i + 3 < n_edges) {
        int4 s = *reinterpret_cast<const int4*>(src + i);
        int4 d = *reinterpret_cast<const int4*>(dst + i);
        int4 w = *reinterpret_cast<const int4*>(widx + i);
        unsafeAtomicAdd(&y[d.x], Param_W[w.x] * x[s.x]);
        unsafeAtomicAdd(&y[d.y], Param_W[w.y] * x[s.y]);
        unsafeAtomicAdd(&y[d.z], Param_W[w.z] * x[s.z]);
        unsafeAtomicAdd(&y[d.w], Param_W[w.w] * x[s.w]);
    } else {
        for (; i < n_edges; ++i)
            unsafeAtomicAdd(&y[dst[i]], Param_W[widx[i]] * x[src[i]]);
    }
}

extern "C" void kernel_launch(void* const* d_in, const int* in_sizes, int n_in,
                              void* d_out, int out_size, void* d_ws, size_t ws_size,
                              hipStream_t stream)
{
    const float* x          = (const float*)d_in[0];
    const float* Param_W    = (const float*)d_in[1];
    const float* Param_b    = (const float*)d_in[2];
    const int*   src        = (const int*)d_in[3];
    const int*   dst        = (const int*)d_in[4];
    const int*   weight_idx = (const int*)d_in[5];
    const int*   node_label = (const int*)d_in[6];
    float* y = (float*)d_out;

    int n_nodes = in_sizes[0];
    int E       = in_sizes[3];

    size_t partials_elems = (size_t)NCHUNKS * PADDED_N;        // 41.8 MB
    size_t need_bytes     = partials_elems * sizeof(float);

    if (ws_size >= need_bytes) {
        float* partials = (float*)d_ws;

        // Fused gather + scan: 160 KB dynamic LDS per block, 1 block/CU
        int chunk = (((E + NCHUNKS - 1) / NCHUNKS) + 3) & ~3;  // mult of 4
        fscan_kernel<<<PARTS * NCHUNKS, TPB_SCAN, NPP * sizeof(float), stream>>>(
            x, Param_W, src, weight_idx, dst, partials, E, chunk);

        reduce5_kernel<<<(n_nodes + 255) / 256, 256, 0, stream>>>(
            partials, Param_b, node_label, y, n_nodes);
    } else {
        bias_init_kernel<<<(n_nodes + 255) / 256, 256, 0, stream>>>(
            Param_b, node_label, y, n_nodes);
        int t = (E + 3) / 4;
        edge_scatter_kernel<<<(t + 255) / 256, 256, 0, stream>>>(
            x, Param_W, src, dst, weight_idx, y, E);
    }
}

// Round 9
// 365.377 us; speedup vs baseline: 1.0647x; 1.0255x over previous
//
#include <hip/hip_runtime.h>

// ---------------- Broadcast-5 fused constants ----------------
#define PARTS 5
#define NPP 40960                  // nodes per partition; 5*40960 = 204800 >= 200000
#define PADDED_N (PARTS * NPP)     // 204800
#define NXCD 8
#define GRP 6                      // chunk-groups per XCD
#define NCHUNKS (NXCD * GRP)       // 48 chunks; grid = 48*5 = 240 blocks (<=256, 1/CU)
#define TPB_SCAN 1024

typedef int   vint4   __attribute__((ext_vector_type(4)));
typedef float vfloat4 __attribute__((ext_vector_type(4)));

// ---------------- Fused phase: gather + 5-partition broadcast scan ----------------
// XCD-aware mapping: blocks B, B+8, B+16, B+24, B+32 (same B%8) are the five
// partition-readers of one chunk and land on the SAME XCD (dispatch is
// round-robin by blockIdx%8). They progress in lockstep, so each stream line
// is fetched beyond-L2 once and served 4x from that XCD's 4MB L2.
// (Round-8 lesson: c-major consecutive blockIdx = 5 different XCDs = 5x fetch.)
__global__ __launch_bounds__(TPB_SCAN) void fscan_kernel(
    const float* __restrict__ x, const float* __restrict__ W,
    const int* __restrict__ src, const int* __restrict__ widx,
    const int* __restrict__ dst,
    float* __restrict__ partials, int E, int chunk)
{
    extern __shared__ float acc[];   // NPP floats = 160 KB
    int xcd = blockIdx.x % NXCD;
    int q   = blockIdx.x / NXCD;     // [0, 30)
    int p   = q % PARTS;
    int g   = q / PARTS;             // [0, GRP)
    int c   = g * NXCD + xcd;        // chunk id in [0, 48)

    float4* a4 = reinterpret_cast<float4*>(acc);
    for (int i = threadIdx.x; i < NPP / 4; i += TPB_SCAN)
        a4[i] = make_float4(0.f, 0.f, 0.f, 0.f);
    __syncthreads();

    int lo = c * chunk;              // chunk is a multiple of 4
    int hi = min(E, lo + chunk);     // E is a multiple of 4
    int base = p * NPP;

    const vint4* d4 = reinterpret_cast<const vint4*>(dst);
    const vint4* s4 = reinterpret_cast<const vint4*>(src);
    const vint4* w4 = reinterpret_cast<const vint4*>(widx);

    #pragma unroll 4
    for (int gi = lo / 4 + threadIdx.x; gi < hi / 4; gi += TPB_SCAN) {
        vint4 d = d4[gi];
        vint4 s = s4[gi];
        vint4 w = w4[gi];

        unsigned r0 = (unsigned)(d.x - base);
        unsigned r1 = (unsigned)(d.y - base);
        unsigned r2 = (unsigned)(d.z - base);
        unsigned r3 = (unsigned)(d.w - base);

        // issue all owned gathers first (exec-masked), then the LDS atomics
        float m0 = 0.f, m1 = 0.f, m2 = 0.f, m3 = 0.f;
        if (r0 < NPP) m0 = W[w.x] * x[s.x];
        if (r1 < NPP) m1 = W[w.y] * x[s.y];
        if (r2 < NPP) m2 = W[w.z] * x[s.z];
        if (r3 < NPP) m3 = W[w.w] * x[s.w];
        if (r0 < NPP) atomicAdd(&acc[r0], m0);
        if (r1 < NPP) atomicAdd(&acc[r1], m1);
        if (r2 < NPP) atomicAdd(&acc[r2], m2);
        if (r3 < NPP) atomicAdd(&acc[r3], m3);
    }
    __syncthreads();

    vfloat4* out4 = reinterpret_cast<vfloat4*>(partials + (size_t)c * PADDED_N + base);
    const vfloat4* av4 = reinterpret_cast<const vfloat4*>(acc);
    for (int i = threadIdx.x; i < NPP / 4; i += TPB_SCAN)
        __builtin_nontemporal_store(av4[i], out4 + i);
}

// ---------------- Reduce: 48 slices + bias ----------------
__global__ __launch_bounds__(256) void reduce5_kernel(
    const float* __restrict__ partials, const float* __restrict__ bias,
    const int* __restrict__ label, float* __restrict__ y, int n)
{
    int i = blockIdx.x * 256 + threadIdx.x;
    if (i >= n) return;
    float s0 = bias[label[i]];
    float s1 = 0.f, s2 = 0.f, s3 = 0.f;
    const float* p = partials + i;
    #pragma unroll 1
    for (int c = 0; c < NCHUNKS; c += 4) {
        s0 += __builtin_nontemporal_load(p + (size_t)(c + 0) * PADDED_N);
        s1 += __builtin_nontemporal_load(p + (size_t)(c + 1) * PADDED_N);
        s2 += __builtin_nontemporal_load(p + (size_t)(c + 2) * PADDED_N);
        s3 += __builtin_nontemporal_load(p + (size_t)(c + 3) * PADDED_N);
    }
    y[i] = (s0 + s1) + (s2 + s3);
}

// ---------------- Fallback (direct atomics) if ws too small ----------------
__global__ __launch_bounds__(256) void bias_init_kernel(
    const float* __restrict__ Param_b, const int* __restrict__ node_label,
    float* __restrict__ y, int n_nodes)
{
    int i = blockIdx.x * blockDim.x + threadIdx.x;
    if (i < n_nodes) y[i] = Param_b[node_label[i]];
}

__global__ __launch_bounds__(256) void edge_scatter_kernel(
    const float* __restrict__ x, const float* __restrict__ Param_W,
    const int* __restrict__ src, const int* __restrict__ dst,
    const int* __restrict__ widx, float* __restrict__ y, int n_edges)
{
    int i = (blockIdx.x * blockDim.x + threadIdx.x) * 4;
    if (i + 3 < n_edges) {
        int4 s = *reinterpret_cast<const int4*>(src + i);
        int4 d = *reinterpret_cast<const int4*>(dst + i);
        int4 w = *reinterpret_cast<const int4*>(widx + i);
        unsafeAtomicAdd(&y[d.x], Param_W[w.x] * x[s.x]);
        unsafeAtomicAdd(&y[d.y], Param_W[w.y] * x[s.y]);
        unsafeAtomicAdd(&y[d.z], Param_W[w.z] * x[s.z]);
        unsafeAtomicAdd(&y[d.w], Param_W[w.w] * x[s.w]);
    } else {
        for (; i < n_edges; ++i)
            unsafeAtomicAdd(&y[dst[i]], Param_W[widx[i]] * x[src[i]]);
    }
}

extern "C" void kernel_launch(void* const* d_in, const int* in_sizes, int n_in,
                              void* d_out, int out_size, void* d_ws, size_t ws_size,
                              hipStream_t stream)
{
    const float* x          = (const float*)d_in[0];
    const float* Param_W    = (const float*)d_in[1];
    const float* Param_b    = (const float*)d_in[2];
    const int*   src        = (const int*)d_in[3];
    const int*   dst        = (const int*)d_in[4];
    const int*   weight_idx = (const int*)d_in[5];
    const int*   node_label = (const int*)d_in[6];
    float* y = (float*)d_out;

    int n_nodes = in_sizes[0];
    int E       = in_sizes[3];

    size_t partials_elems = (size_t)NCHUNKS * PADDED_N;        // 39.3 MB
    size_t need_bytes     = partials_elems * sizeof(float);

    if (ws_size >= need_bytes) {
        float* partials = (float*)d_ws;

        // Fused gather + scan: 160 KB dynamic LDS, 240 blocks (1/CU, XCD-mapped)
        int chunk = (((E + NCHUNKS - 1) / NCHUNKS) + 3) & ~3;  // mult of 4
        fscan_kernel<<<PARTS * NCHUNKS, TPB_SCAN, NPP * sizeof(float), stream>>>(
            x, Param_W, src, weight_idx, dst, partials, E, chunk);

        reduce5_kernel<<<(n_nodes + 255) / 256, 256, 0, stream>>>(
            partials, Param_b, node_label, y, n_nodes);
    } else {
        bias_init_kernel<<<(n_nodes + 255) / 256, 256, 0, stream>>>(
            Param_b, node_label, y, n_nodes);
        int t = (E + 3) / 4;
        edge_scatter_kernel<<<(t + 255) / 256, 256, 0, stream>>>(
            x, Param_W, src, dst, weight_idx, y, E);
    }
}

// Round 10
// 329.996 us; speedup vs baseline: 1.1789x; 1.1072x over previous
//
#include <hip/hip_runtime.h>
#include <hip/hip_fp16.h>

// ---------------- Broadcast-5 fused constants ----------------
#define PARTS 5
#define NPP 40960                  // nodes per partition; 5*40960 = 204800 >= 200000
#define PADDED_N (PARTS * NPP)     // 204800
#define NXCD 8
#define GRP 6                      // chunk-groups per XCD
#define NCHUNKS (NXCD * GRP)       // 48 chunks; grid = 48*5 = 240 blocks (<=256, 1/CU)
#define TPB_SCAN 1024

typedef int   vint4   __attribute__((ext_vector_type(4)));
typedef float vfloat4 __attribute__((ext_vector_type(4)));

// ---------------- Phase 0: W f32 -> f16 (2MB table => fits L2 with x) ----------------
__global__ __launch_bounds__(256) void wconv_kernel(
    const float* __restrict__ W, __half* __restrict__ Wh, int n)
{
    int i4 = (blockIdx.x * 256 + threadIdx.x) * 4;
    if (i4 + 3 < n) {
        vfloat4 w = *reinterpret_cast<const vfloat4*>(W + i4);
        __half2 h01 = __floats2half2_rn(w.x, w.y);
        __half2 h23 = __floats2half2_rn(w.z, w.w);
        *reinterpret_cast<__half2*>(Wh + i4)     = h01;
        *reinterpret_cast<__half2*>(Wh + i4 + 2) = h23;
    } else {
        for (; i4 < n; ++i4) Wh[i4] = __float2half(W[i4]);
    }
}

// ---------------- Fused phase: gather + 5-partition broadcast scan ----------------
// XCD-aware mapping (round-9 lesson, FETCH 804->312 MB): the 5 partition-readers
// of a chunk share blockIdx%8 -> same XCD -> stream lines fetched beyond-L2 once.
// fp16 W (round-10): Wh (2MB) + x (0.8MB) < 4MB L2 -> gathers are L2 hits.
__global__ __launch_bounds__(TPB_SCAN) void fscan_kernel(
    const float* __restrict__ x, const __half* __restrict__ Wh,
    const int* __restrict__ src, const int* __restrict__ widx,
    const int* __restrict__ dst,
    float* __restrict__ partials, int E, int chunk)
{
    extern __shared__ float acc[];   // NPP floats = 160 KB
    int xcd = blockIdx.x % NXCD;
    int q   = blockIdx.x / NXCD;     // [0, 30)
    int p   = q % PARTS;
    int g   = q / PARTS;             // [0, GRP)
    int c   = g * NXCD + xcd;        // chunk id in [0, 48)

    float4* a4 = reinterpret_cast<float4*>(acc);
    for (int i = threadIdx.x; i < NPP / 4; i += TPB_SCAN)
        a4[i] = make_float4(0.f, 0.f, 0.f, 0.f);
    __syncthreads();

    int lo = c * chunk;              // chunk is a multiple of 4
    int hi = min(E, lo + chunk);     // E is a multiple of 4
    int base = p * NPP;

    const vint4* d4 = reinterpret_cast<const vint4*>(dst);
    const vint4* s4 = reinterpret_cast<const vint4*>(src);
    const vint4* w4 = reinterpret_cast<const vint4*>(widx);

    #pragma unroll 4
    for (int gi = lo / 4 + threadIdx.x; gi < hi / 4; gi += TPB_SCAN) {
        vint4 d = d4[gi];
        vint4 s = s4[gi];
        vint4 w = w4[gi];

        unsigned r0 = (unsigned)(d.x - base);
        unsigned r1 = (unsigned)(d.y - base);
        unsigned r2 = (unsigned)(d.z - base);
        unsigned r3 = (unsigned)(d.w - base);

        // issue all owned gathers first (exec-masked), then the LDS atomics
        float m0 = 0.f, m1 = 0.f, m2 = 0.f, m3 = 0.f;
        if (r0 < NPP) m0 = __half2float(Wh[w.x]) * x[s.x];
        if (r1 < NPP) m1 = __half2float(Wh[w.y]) * x[s.y];
        if (r2 < NPP) m2 = __half2float(Wh[w.z]) * x[s.z];
        if (r3 < NPP) m3 = __half2float(Wh[w.w]) * x[s.w];
        if (r0 < NPP) atomicAdd(&acc[r0], m0);
        if (r1 < NPP) atomicAdd(&acc[r1], m1);
        if (r2 < NPP) atomicAdd(&acc[r2], m2);
        if (r3 < NPP) atomicAdd(&acc[r3], m3);
    }
    __syncthreads();

    vfloat4* out4 = reinterpret_cast<vfloat4*>(partials + (size_t)c * PADDED_N + base);
    const vfloat4* av4 = reinterpret_cast<const vfloat4*>(acc);
    for (int i = threadIdx.x; i < NPP / 4; i += TPB_SCAN)
        __builtin_nontemporal_store(av4[i], out4 + i);
}

// ---------------- Reduce: 48 slices + bias ----------------
__global__ __launch_bounds__(256) void reduce5_kernel(
    const float* __restrict__ partials, const float* __restrict__ bias,
    const int* __restrict__ label, float* __restrict__ y, int n)
{
    int i = blockIdx.x * 256 + threadIdx.x;
    if (i >= n) return;
    float s0 = bias[label[i]];
    float s1 = 0.f, s2 = 0.f, s3 = 0.f;
    const float* p = partials + i;
    #pragma unroll 1
    for (int c = 0; c < NCHUNKS; c += 4) {
        s0 += __builtin_nontemporal_load(p + (size_t)(c + 0) * PADDED_N);
        s1 += __builtin_nontemporal_load(p + (size_t)(c + 1) * PADDED_N);
        s2 += __builtin_nontemporal_load(p + (size_t)(c + 2) * PADDED_N);
        s3 += __builtin_nontemporal_load(p + (size_t)(c + 3) * PADDED_N);
    }
    y[i] = (s0 + s1) + (s2 + s3);
}

// ---------------- Fallback (direct atomics) if ws too small ----------------
__global__ __launch_bounds__(256) void bias_init_kernel(
    const float* __restrict__ Param_b, const int* __restrict__ node_label,
    float* __restrict__ y, int n_nodes)
{
    int i = blockIdx.x * blockDim.x + threadIdx.x;
    if (i < n_nodes) y[i] = Param_b[node_label[i]];
}

__global__ __launch_bounds__(256) void edge_scatter_kernel(
    const float* __restrict__ x, const float* __restrict__ Param_W,
    const int* __restrict__ src, const int* __restrict__ dst,
    const int* __restrict__ widx, float* __restrict__ y, int n_edges)
{
    int i = (blockIdx.x * blockDim.x + threadIdx.x) * 4;
    if (i + 3 < n_edges) {
        int4 s = *reinterpret_cast<const int4*>(src + i);
        int4 d = *reinterpret_cast<const int4*>(dst + i);
        int4 w = *reinterpret_cast<const int4*>(widx + i);
        unsafeAtomicAdd(&y[d.x], Param_W[w.x] * x[s.x]);
        unsafeAtomicAdd(&y[d.y], Param_W[w.y] * x[s.y]);
        unsafeAtomicAdd(&y[d.z], Param_W[w.z] * x[s.z]);
        unsafeAtomicAdd(&y[d.w], Param_W[w.w] * x[s.w]);
    } else {
        for (; i < n_edges; ++i)
            unsafeAtomicAdd(&y[dst[i]], Param_W[widx[i]] * x[src[i]]);
    }
}

extern "C" void kernel_launch(void* const* d_in, const int* in_sizes, int n_in,
                              void* d_out, int out_size, void* d_ws, size_t ws_size,
                              hipStream_t stream)
{
    const float* x          = (const float*)d_in[0];
    const float* Param_W    = (const float*)d_in[1];
    const float* Param_b    = (const float*)d_in[2];
    const int*   src        = (const int*)d_in[3];
    const int*   dst        = (const int*)d_in[4];
    const int*   weight_idx = (const int*)d_in[5];
    const int*   node_label = (const int*)d_in[6];
    float* y = (float*)d_out;

    int n_nodes = in_sizes[0];
    int W_n     = in_sizes[1];
    int E       = in_sizes[3];

    size_t wh_bytes       = ((size_t)W_n * sizeof(__half) + 255) & ~(size_t)255;  // 2MB
    size_t partials_elems = (size_t)NCHUNKS * PADDED_N;                            // 39.3 MB
    size_t need_bytes     = wh_bytes + partials_elems * sizeof(float);

    if (ws_size >= need_bytes) {
        __half* Wh      = (__half*)d_ws;
        float*  partials = (float*)((char*)d_ws + wh_bytes);

        // Phase 0: convert W to fp16 (ws is re-poisoned every launch, so always rerun)
        int t0 = (W_n + 3) / 4;
        wconv_kernel<<<(t0 + 255) / 256, 256, 0, stream>>>(Param_W, Wh, W_n);

        // Fused gather + scan: 160 KB dynamic LDS, 240 blocks (1/CU, XCD-mapped)
        int chunk = (((E + NCHUNKS - 1) / NCHUNKS) + 3) & ~3;  // mult of 4
        fscan_kernel<<<PARTS * NCHUNKS, TPB_SCAN, NPP * sizeof(float), stream>>>(
            x, Wh, src, weight_idx, dst, partials, E, chunk);

        reduce5_kernel<<<(n_nodes + 255) / 256, 256, 0, stream>>>(
            partials, Param_b, node_label, y, n_nodes);
    } else {
        bias_init_kernel<<<(n_nodes + 255) / 256, 256, 0, stream>>>(
            Param_b, node_label, y, n_nodes);
        int t = (E + 3) / 4;
        edge_scatter_kernel<<<(t + 255) / 256, 256, 0, stream>>>(
            x, Param_W, src, dst, weight_idx, y, E);
    }
}